// Round 14
// baseline (340.851 us; speedup 1.0000x reference)
//
#include <hip/hip_runtime.h>

#define HH 4
#define FF 128
#define DD 32

typedef float f32x4 __attribute__((ext_vector_type(4)));
typedef _Float16 h16x8 __attribute__((ext_vector_type(8)));
typedef _Float16 h16x4 __attribute__((ext_vector_type(4)));
typedef _Float16 h16x2 __attribute__((ext_vector_type(2)));

// ---------------- prep: zero counts + fp16 weight tables ----------------

__global__ __launch_bounds__(256) void prep_kernel(
    const float* __restrict__ wq, const float* __restrict__ wk,
    _Float16* __restrict__ wqT, _Float16* __restrict__ wkT,
    _Float16* __restrict__ wkD, int* __restrict__ counts, int N) {
    int i = blockIdx.x * 256 + threadIdx.x;
    if (i < 16384) {
        int c = i >> 7, f = i & 127;
        int h = c >> 5, d = c & 31;
        wqT[i] = (_Float16)wq[h * 4096 + f * 32 + d];
        wkT[i] = (_Float16)wk[h * 4096 + f * 32 + d];
        wkD[i] = (_Float16)wk[i];
    }
    if (i < N + 2) counts[i] = 0;
}

// ---------------- scatter (sort): 2 edges/thread, vectorized ----------------

__global__ void scatter_kernel(const int* __restrict__ src, const int* __restrict__ dst,
                               int* __restrict__ cursor, int2* __restrict__ ed, int E) {
    int i = (blockIdx.x * blockDim.x + threadIdx.x) * 2;
    if (i + 1 < E) {
        int2 s2 = *(const int2*)(src + i);
        int2 d2 = *(const int2*)(dst + i);
        int p0 = atomicAdd(&cursor[s2.x], 1);
        int p1 = atomicAdd(&cursor[s2.y], 1);
        long long pk0 = (unsigned)i | ((long long)d2.x << 32);
        long long pk1 = (unsigned)(i + 1) | ((long long)d2.y << 32);
        __builtin_nontemporal_store(pk0, (long long*)&ed[p0]);
        __builtin_nontemporal_store(pk1, (long long*)&ed[p1]);
    } else if (i < E) {
        int pos = atomicAdd(&cursor[src[i]], 1);
        long long pack = (unsigned)i | ((long long)dst[i] << 32);
        __builtin_nontemporal_store(pack, (long long*)&ed[pos]);
    }
}

// ---------------- fused: q+k projection via MFMA + histogram ----------------

__global__ __launch_bounds__(256) void qk_mfma_hist(
    const float* __restrict__ feat, const _Float16* __restrict__ wqT,
    const _Float16* __restrict__ wkT, _Float16* __restrict__ q16,
    _Float16* __restrict__ k16, int N,
    const int* __restrict__ src, int* __restrict__ counts, int E, int QKB) {
    int bid = blockIdx.x;
    if (bid >= QKB) {           // ---- histogram role ----
        int i = ((bid - QKB) * 256 + threadIdx.x) * 4;
        if (i + 3 < E) {
            int4 v = *(const int4*)(src + i);
            atomicAdd(&counts[v.x], 1);
            atomicAdd(&counts[v.y], 1);
            atomicAdd(&counts[v.z], 1);
            atomicAdd(&counts[v.w], 1);
        } else {
            for (; i < E; ++i) atomicAdd(&counts[src[i]], 1);
        }
        return;
    }
    int wid = threadIdx.x >> 6, lane = threadIdx.x & 63;
    int n0 = bid * 64 + wid * 16;
    if (n0 >= N) return;
    int lrow = lane & 15, lk = lane >> 4;
    int arow = n0 + lrow; if (arow >= N) arow = N - 1;

    f32x4 accq[8], acck[8];
#pragma unroll
    for (int t = 0; t < 8; ++t) { accq[t] = (f32x4){0.f,0.f,0.f,0.f}; acck[t] = (f32x4){0.f,0.f,0.f,0.f}; }

#pragma unroll
    for (int ks = 0; ks < 4; ++ks) {
        const float* ap = feat + (size_t)arow * FF + ks * 32 + lk * 8;
        h16x8 a;
#pragma unroll
        for (int j = 0; j < 8; ++j) a[j] = (_Float16)ap[j];
#pragma unroll
        for (int t = 0; t < 8; ++t) {
            h16x8 b1 = *(const h16x8*)(wqT + (size_t)(t * 16 + lrow) * FF + ks * 32 + lk * 8);
            h16x8 b2 = *(const h16x8*)(wkT + (size_t)(t * 16 + lrow) * FF + ks * 32 + lk * 8);
            accq[t] = __builtin_amdgcn_mfma_f32_16x16x32_f16(a, b1, accq[t], 0, 0, 0);
            acck[t] = __builtin_amdgcn_mfma_f32_16x16x32_f16(a, b2, acck[t], 0, 0, 0);
        }
    }
#pragma unroll
    for (int r = 0; r < 4; ++r) {
        int n = n0 + lk * 4 + r;
        if (n < N) {
#pragma unroll
            for (int t = 0; t < 8; ++t) {
                q16[(size_t)n * FF + t * 16 + lrow] = (_Float16)accq[t][r];
                k16[(size_t)n * FF + t * 16 + lrow] = (_Float16)acck[t][r];
            }
        }
    }
}

// ---------------- fused: kk via MFMA + group-offset alloc ----------------

__global__ __launch_bounds__(256) void kk_alloc_kernel(
    const _Float16* __restrict__ k16, const _Float16* __restrict__ wkD,
    _Float16* __restrict__ kk16, int N,
    const int* __restrict__ counts, int* __restrict__ startb,
    int* __restrict__ cursor, int* __restrict__ gcur, int KKB) {
    int bid = blockIdx.x;
    if (bid >= KKB) {           // ---- alloc role: wave scan + one atomic ----
        int sid = (bid - KKB) * 256 + threadIdx.x;
        int lane = threadIdx.x & 63;
        int cnt = (sid < N) ? counts[sid] : 0;
        int incl = cnt;
#pragma unroll
        for (int off = 1; off < 64; off <<= 1) {
            int y = __shfl_up(incl, off, 64);
            if (lane >= off) incl += y;
        }
        int total = __shfl(incl, 63, 64);
        int base = 0;
        if (lane == 63) base = atomicAdd(gcur, total);
        base = __shfl(base, 63, 64);
        if (sid < N) {
            int st = base + incl - cnt;
            startb[sid] = st;
            cursor[sid] = st;
        }
        return;
    }
    int wid = threadIdx.x >> 6, lane = threadIdx.x & 63;
    int n0 = bid * 64 + wid * 16;
    if (n0 >= N) return;
    int lrow = lane & 15, lk = lane >> 4;
    int arow = n0 + lrow; if (arow >= N) arow = N - 1;

#pragma unroll
    for (int h = 0; h < HH; ++h) {
        h16x8 a = *(const h16x8*)(k16 + (size_t)arow * FF + h * 32 + lk * 8);
        f32x4 acc[8];
#pragma unroll
        for (int t = 0; t < 8; ++t) acc[t] = (f32x4){0.f,0.f,0.f,0.f};
#pragma unroll
        for (int t = 0; t < 8; ++t) {
            h16x8 b = *(const h16x8*)(wkD + (size_t)h * 4096 + (size_t)(t * 16 + lrow) * 32 + lk * 8);
            acc[t] = __builtin_amdgcn_mfma_f32_16x16x32_f16(a, b, acc[t], 0, 0, 0);
        }
#pragma unroll
        for (int r = 0; r < 4; ++r) {
            int n = n0 + lk * 4 + r;
            if (n < N) {
#pragma unroll
                for (int t = 0; t < 8; ++t)
                    kk16[(size_t)n * 512 + h * FF + t * 16 + lrow] = (_Float16)acc[t][r];
            }
        }
    }
}

// ---------------- group kernel: r13 + LDS perm cache for epilogue ----------------

__device__ __forceinline__ void score_row(   // slow-path helper
    const float* __restrict__ rel, const _Float16* __restrict__ k,
    int e_i, int dd, int t,
    const float4* kkA, const float4* kkB, const float2* qv, float* ev) {
    const float* rp = rel + (size_t)e_i * FF + t * 8;
    f32x4 r0 = __builtin_nontemporal_load((const f32x4*)rp);
    f32x4 r1 = __builtin_nontemporal_load((const f32x4*)(rp + 4));
#pragma unroll
    for (int h = 0; h < HH; ++h) {
        h16x2 kvh = *(const h16x2*)(k + ((size_t)dd * HH + h) * DD + t * 2);
        float a = r0.x * kkA[h].x + r0.y * kkA[h].y + r0.z * kkA[h].z + r0.w * kkA[h].w
                + r1.x * kkB[h].x + r1.y * kkB[h].y + r1.z * kkB[h].z + r1.w * kkB[h].w
                + qv[h].x * (float)kvh.x + qv[h].y * (float)kvh.y;
#pragma unroll
        for (int off = 1; off < 16; off <<= 1) a += __shfl_xor(a, off, 64);
        ev[h] = a >= 0.f ? a : 0.01f * a;
    }
}

__global__ __launch_bounds__(256) void group_kernel(
    const float* __restrict__ rel, const int2* __restrict__ ed,
    const _Float16* __restrict__ q, const _Float16* __restrict__ k,
    const _Float16* __restrict__ kk, const int* __restrict__ start,
    const int* __restrict__ counts, float* __restrict__ out, int N) {
    __shared__ __align__(16) float e_buf_all[4][128][4];
    __shared__ int p_buf_all[4][128];
    int wid = threadIdx.x >> 6;
    int s = blockIdx.x * 4 + wid;
    if (s >= N) return;
    int cnt = counts[s];
    if (cnt == 0) return;
    int base = start[s];
    int lane = threadIdx.x & 63;
    int g = lane >> 4, t = lane & 15;
    int hsel = ((t & 1) << 1) | ((t & 2) >> 1);
    float (*e_buf)[4] = e_buf_all[wid];
    int* p_buf = p_buf_all[wid];

    float4 kkA[HH], kkB[HH];
    float2 qv[HH];
    const _Float16* kkbase = kk + (size_t)s * (HH * FF) + t * 8;
    const _Float16* qbase  = q  + (size_t)s * (HH * DD) + t * 2;
#pragma unroll
    for (int h = 0; h < HH; ++h) {
        h16x4 a = *(const h16x4*)(kkbase + h * FF);
        h16x4 b = *(const h16x4*)(kkbase + h * FF + 4);
        kkA[h] = make_float4((float)a.x, (float)a.y, (float)a.z, (float)a.w);
        kkB[h] = make_float4((float)b.x, (float)b.y, (float)b.z, (float)b.w);
        h16x2 qh = *(const h16x2*)(qbase + h * DD);
        qv[h] = make_float2((float)qh.x, (float)qh.y);
    }

    float mloc = -INFINITY;
    bool fast = (cnt <= 128);

    for (int c0 = 0; c0 < cnt; c0 += 64) {
        int nc = min(cnt - c0, 64);
        int pv = 0, dv = 0;
        if (lane < nc) {
            int2 pd = ed[base + c0 + lane];
            pv = pd.x; dv = pd.y;
            if (fast) p_buf[c0 + lane] = pv;
        }
        for (int j0 = 0; j0 < nc; j0 += 4) {
            int idx = j0 + g;
            int sel = idx < nc ? idx : 0;
            int e_i = __shfl(pv, sel, 64);
            int dd  = __shfl(dv, sel, 64);
            const float* rp = rel + (size_t)e_i * FF + t * 8;
            f32x4 r0 = __builtin_nontemporal_load((const f32x4*)rp);
            f32x4 r1 = __builtin_nontemporal_load((const f32x4*)(rp + 4));
            float p[HH];
#pragma unroll
            for (int h = 0; h < HH; ++h) {
                h16x2 kvh = *(const h16x2*)(k + ((size_t)dd * HH + h) * DD + t * 2);
                p[h] = r0.x * kkA[h].x + r0.y * kkA[h].y + r0.z * kkA[h].z + r0.w * kkA[h].w
                     + r1.x * kkB[h].x + r1.y * kkB[h].y + r1.z * kkB[h].z + r1.w * kkB[h].w
                     + qv[h].x * (float)kvh.x + qv[h].y * (float)kvh.y;
            }
            float sx = (t & 1) ? p[0] : p[2];
            float sy = (t & 1) ? p[1] : p[3];
            float rx = __shfl_xor(sx, 1, 64);
            float ry = __shfl_xor(sy, 1, 64);
            float a0 = ((t & 1) ? p[2] : p[0]) + rx;
            float a1 = ((t & 1) ? p[3] : p[1]) + ry;
            float sz = (t & 2) ? a0 : a1;
            float rz = __shfl_xor(sz, 2, 64);
            float e = ((t & 2) ? a1 : a0) + rz;
            e += __shfl_xor(e, 4, 64);
            e += __shfl_xor(e, 8, 64);
            e = e >= 0.f ? e : 0.01f * e;
            if (idx < nc) {
                mloc = fmaxf(mloc, e);
                if (fast && t < 4) e_buf[c0 + idx][hsel] = e;
            }
        }
    }
    mloc = fmaxf(mloc, __shfl_xor(mloc, 16, 64));
    mloc = fmaxf(mloc, __shfl_xor(mloc, 32, 64));
    float m[HH];
    m[0] = __shfl(mloc, 0, 64);
    m[1] = __shfl(mloc, 2, 64);
    m[2] = __shfl(mloc, 1, 64);
    m[3] = __shfl(mloc, 3, 64);

    if (fast) {
        int i0 = lane, i1 = lane + 64;
        float ex0[HH] = {0.f, 0.f, 0.f, 0.f}, ex1[HH] = {0.f, 0.f, 0.f, 0.f};
        if (i0 < cnt) {
            float4 ev = *(const float4*)e_buf[i0];
            ex0[0] = __expf(ev.x - m[0]); ex0[1] = __expf(ev.y - m[1]);
            ex0[2] = __expf(ev.z - m[2]); ex0[3] = __expf(ev.w - m[3]);
        }
        if (i1 < cnt) {
            float4 ev = *(const float4*)e_buf[i1];
            ex1[0] = __expf(ev.x - m[0]); ex1[1] = __expf(ev.y - m[1]);
            ex1[2] = __expf(ev.z - m[2]); ex1[3] = __expf(ev.w - m[3]);
        }
        float rl[HH];
#pragma unroll
        for (int h = 0; h < HH; ++h) {
            float v = ex0[h] + ex1[h];
#pragma unroll
            for (int off = 1; off < 64; off <<= 1) v += __shfl_xor(v, off, 64);
            rl[h] = 1.0f / v;
        }
        if (i0 < cnt)
            out[p_buf[i0]] = 0.25f * (ex0[0]*rl[0] + ex0[1]*rl[1] + ex0[2]*rl[2] + ex0[3]*rl[3]);
        if (i1 < cnt)
            out[p_buf[i1]] = 0.25f * (ex1[0]*rl[0] + ex1[1]*rl[1] + ex1[2]*rl[2] + ex1[3]*rl[3]);
    } else {
        float lacc[HH] = {0.f, 0.f, 0.f, 0.f};
        for (int c0 = 0; c0 < cnt; c0 += 64) {
            int nc = min(cnt - c0, 64);
            int pv = 0, dv = 0;
            if (lane < nc) { int2 pd = ed[base + c0 + lane]; pv = pd.x; dv = pd.y; }
            for (int j0 = 0; j0 < nc; j0 += 4) {
                int idx = j0 + g;
                int sel = idx < nc ? idx : 0;
                int e_i = __shfl(pv, sel, 64);
                int dd  = __shfl(dv, sel, 64);
                float ev[HH];
                score_row(rel, k, e_i, dd, t, kkA, kkB, qv, ev);
                if (idx < nc && t == 0) {
#pragma unroll
                    for (int h = 0; h < HH; ++h) lacc[h] += __expf(ev[h] - m[h]);
                }
            }
        }
        float rl[HH];
#pragma unroll
        for (int h = 0; h < HH; ++h) {
            float v = lacc[h];
#pragma unroll
            for (int off = 1; off < 64; off <<= 1) v += __shfl_xor(v, off, 64);
            rl[h] = 1.0f / v;
        }
        for (int c0 = 0; c0 < cnt; c0 += 64) {
            int nc = min(cnt - c0, 64);
            int pv = 0, dv = 0;
            if (lane < nc) { int2 pd = ed[base + c0 + lane]; pv = pd.x; dv = pd.y; }
            for (int j0 = 0; j0 < nc; j0 += 4) {
                int idx = j0 + g;
                int sel = idx < nc ? idx : 0;
                int e_i = __shfl(pv, sel, 64);
                int dd  = __shfl(dv, sel, 64);
                float ev[HH];
                score_row(rel, k, e_i, dd, t, kkA, kkB, qv, ev);
                if (idx < nc && t == 0) {
                    float a = __expf(ev[0]-m[0])*rl[0] + __expf(ev[1]-m[1])*rl[1]
                            + __expf(ev[2]-m[2])*rl[2] + __expf(ev[3]-m[3])*rl[3];
                    out[e_i] = 0.25f * a;
                }
            }
        }
    }
}

extern "C" void kernel_launch(void* const* d_in, const int* in_sizes, int n_in,
                              void* d_out, int out_size, void* d_ws, size_t ws_size,
                              hipStream_t stream) {
    const float* feat = (const float*)d_in[0];   // (N,1,F)
    const float* rel  = (const float*)d_in[1];   // (E,1,F)
    const int*   src  = (const int*)d_in[2];
    const int*   dst  = (const int*)d_in[3];
    const float* wq   = (const float*)d_in[4];   // (H,F,D)
    const float* wk   = (const float*)d_in[5];
    float* out = (float*)d_out;

    const int N = in_sizes[0] / FF;
    const int E = in_sizes[2];

    _Float16* q16  = (_Float16*)d_ws;                 // N*128
    _Float16* k16  = q16 + (size_t)N * FF;            // N*128
    _Float16* kk16 = k16 + (size_t)N * FF;            // N*512
    _Float16* wqT  = kk16 + (size_t)N * 512;          // 16384
    _Float16* wkT  = wqT + 16384;                     // 16384
    _Float16* wkD  = wkT + 16384;                     // 16384
    int* counts    = (int*)(wkD + 16384);             // N
    int* gcur      = counts + N;                      // 1 (+1 pad)
    int* start     = gcur + 2;                        // N
    int* cursor    = start + N;                       // N
    int2* ed       = (int2*)(cursor + N);             // E

    int nb   = (N + 255) / 256;
    int QKB  = (N + 63) / 64;
    int HB   = (E + 1023) / 1024;
    int KKB  = (N + 63) / 64;
    int PREP = 16384 > N + 2 ? (16384 + 255) / 256 : (N + 2 + 255) / 256;

    prep_kernel<<<PREP, 256, 0, stream>>>(wq, wk, wqT, wkT, wkD, counts, N);
    qk_mfma_hist<<<QKB + HB, 256, 0, stream>>>(feat, wqT, wkT, q16, k16, N, src, counts, E, QKB);
    kk_alloc_kernel<<<KKB + nb, 256, 0, stream>>>(k16, wkD, kk16, N, counts, start, cursor, gcur, KKB);
    scatter_kernel<<<(E / 2 + 255) / 256, 256, 0, stream>>>(src, dst, cursor, ed, E);
    group_kernel<<<(N + 3) / 4, 256, 0, stream>>>(rel, ed, q16, k16, kk16, start, counts, out, N);
}